// Round 13
// baseline (121.244 us; speedup 1.0000x reference)
//
#include <hip/hip_runtime.h>
#include <float.h>
#include <math.h>

// AdvancedLossFunction: total = 1.0*occ + 0.1*smooth + 0.01*sparse + 0.1*cons
// 2 dispatches. 3-NN via OCTET-min packed-key brute force + packed FP32 math:
//   t(i,j) = -2 p_i.q_j + |q_j|^2  (monotone in d2 per i)
//   knn keeps top-4 of per-octet (8 j's) minima:
//     key = bits(min t of octet) & 0xFFFFF000 | octet_id (11 bits).
//   Coverage: points with t <= t(NN3) are {self,NN1..NN3} -> <= 4 octets -> top-4
//   octet keys always cover them. Merge decodes 4 octets -> 32 candidates,
//   re-evaluates EXACT d2 with index self-exclusion -> absmax ~ 0.
// R12 analysis: VALU ~3.1 ops/pair (~12us floor) but 0.25 ds_read_b128/pair
//   (~20us LDS floor) -> LDS pipe is the knn limiter. ITEMS=8 halves LDS/pair
//   (0.125 -> ~10us), balancing pipes. Occupancy proven irrelevant (R9/R10).
// R7: flat > branchy. R6/R10: no bulk fences (256-block staggered ticket ok).

constexpr int   N_ = 16384;
constexpr int   F_ = 64;
constexpr float OCC_W = 1.0f, SMOOTH_W = 0.1f, SPARSE_W = 0.01f, CONS_W = 0.1f;
constexpr float EPS_ = 1e-7f;

typedef float v2f __attribute__((ext_vector_type(2)));

__device__ __forceinline__ v2f pk_fma(v2f a, v2f b, v2f c) {
  v2f d;
  asm("v_pk_fma_f32 %0, %1, %2, %3" : "=v"(d) : "v"(a), "v"(b), "v"(c));
  return d;
}

__device__ __forceinline__ void ins4f(float t, float& b0, float& b1, float& b2, float& b3) {
  // maintains b0<=b1<=b2<=b3; med3(a,b,t) with a<=b == sorted-insert clamp
  float n0 = fminf(b0, t);
  float n1 = __builtin_amdgcn_fmed3f(b0, b1, t);
  float n2 = __builtin_amdgcn_fmed3f(b1, b2, t);
  float n3 = __builtin_amdgcn_fmed3f(b2, b3, t);
  b0 = n0; b1 = n1; b2 = n2; b3 = n3;
}

// ws layout:
//   0    : float4 part[256]
//   4096 : unsigned done          (zeroed by knn block 0)
//   8192 : float4 cand[CHUNKS][N] (top-4 packed octet keys per (chunk, i))

template <int CHUNKS>
__global__ __launch_bounds__(256) void knn_kernel(const float* __restrict__ pts,
                                                  float4* __restrict__ cand,
                                                  unsigned* __restrict__ done) {
  constexpr int CHUNK   = N_ / CHUNKS;             // 256 at CHUNKS=64
  constexpr int TILE    = CHUNK;
  constexpr int ITEMS   = 8;                       // 8 i's/thread: halves LDS/pair
  constexpr int IPG     = ITEMS * 256;             // 2048
  constexpr int IGROUPS = N_ / IPG;                // 8
  if (blockIdx.x == 0 && threadIdx.x == 0) *done = 0u;

  int igrp  = blockIdx.x % IGROUPS;
  int chunk = blockIdx.x / IGROUPS;
  int j0    = chunk * CHUNK;

  // pair-interleaved SoA: AB[p]=(-2x0,-2x1,-2y0,-2y1), CW[p]=(-2z0,-2z1,|q0|^2,|q1|^2)
  __shared__ float4 AB[TILE / 2];
  __shared__ float4 CW[TILE / 2];
  for (int p = threadIdx.x; p < TILE / 2; p += 256) {
    int ja = j0 + 2 * p, jb = ja + 1;
    float xa = pts[3 * ja], ya = pts[3 * ja + 1], za = pts[3 * ja + 2];
    float xb = pts[3 * jb], yb = pts[3 * jb + 1], zb = pts[3 * jb + 2];
    AB[p] = make_float4(-2.f * xa, -2.f * xb, -2.f * ya, -2.f * yb);
    CW[p] = make_float4(-2.f * za, -2.f * zb,
                        fmaf(xa, xa, fmaf(ya, ya, za * za)),
                        fmaf(xb, xb, fmaf(yb, yb, zb * zb)));
  }

  v2f xi2[ITEMS], yi2[ITEMS], zi2[ITEMS];
  float b0[ITEMS], b1[ITEMS], b2[ITEMS], b3[ITEMS];
#pragma unroll
  for (int k = 0; k < ITEMS; ++k) {
    int i = igrp * IPG + threadIdx.x + k * 256;
    float x = pts[3 * i], y = pts[3 * i + 1], z = pts[3 * i + 2];
    xi2[k] = v2f{x, x}; yi2[k] = v2f{y, y}; zi2[k] = v2f{z, z};
    b0[k] = b1[k] = b2[k] = b3[k] = FLT_MAX;
  }
  __syncthreads();

  unsigned obase = (unsigned)(j0 >> 3);            // global octet id base (2048 octets)
  for (int oct = 0; oct < TILE / 8; ++oct) {
    float4 ab0 = AB[oct * 4 + 0], ab1 = AB[oct * 4 + 1],
           ab2 = AB[oct * 4 + 2], ab3 = AB[oct * 4 + 3];
    float4 cw0 = CW[oct * 4 + 0], cw1 = CW[oct * 4 + 1],
           cw2 = CW[oct * 4 + 2], cw3 = CW[oct * 4 + 3];
    unsigned ok = obase + (unsigned)oct;
#pragma unroll
    for (int k = 0; k < ITEMS; ++k) {
      v2f t0 = pk_fma(xi2[k], v2f{ab0.x, ab0.y},
               pk_fma(yi2[k], v2f{ab0.z, ab0.w},
               pk_fma(zi2[k], v2f{cw0.x, cw0.y}, v2f{cw0.z, cw0.w})));
      v2f t1 = pk_fma(xi2[k], v2f{ab1.x, ab1.y},
               pk_fma(yi2[k], v2f{ab1.z, ab1.w},
               pk_fma(zi2[k], v2f{cw1.x, cw1.y}, v2f{cw1.z, cw1.w})));
      v2f t2 = pk_fma(xi2[k], v2f{ab2.x, ab2.y},
               pk_fma(yi2[k], v2f{ab2.z, ab2.w},
               pk_fma(zi2[k], v2f{cw2.x, cw2.y}, v2f{cw2.z, cw2.w})));
      v2f t3 = pk_fma(xi2[k], v2f{ab3.x, ab3.y},
               pk_fma(yi2[k], v2f{ab3.z, ab3.w},
               pk_fma(zi2[k], v2f{cw3.x, cw3.y}, v2f{cw3.z, cw3.w})));
      float m01 = fminf(fminf(t0.x, t0.y), fminf(t1.x, t1.y));
      float m23 = fminf(fminf(t2.x, t2.y), fminf(t3.x, t3.y));
      float mm  = fminf(m01, m23);
      float kf = __uint_as_float((__float_as_uint(mm) & 0xFFFFF000u) | ok);
      ins4f(kf, b0[k], b1[k], b2[k], b3[k]);
    }
  }

#pragma unroll
  for (int k = 0; k < ITEMS; ++k) {
    int i = igrp * IPG + threadIdx.x + k * 256;
    cand[(size_t)chunk * N_ + i] = make_float4(b0[k], b1[k], b2[k], b3[k]);
  }
}

// grid 256: 64 i's per block, 4 waves scan CHUNKS/4 chunks each; wave 0 merges,
// decodes 4 octets -> 32 candidates, exact d2 + index self-exclusion -> smoothness.
// Plus all scalar reductions. 256-block staggered ticket; last block finalizes.
template <int CHUNKS>
__global__ __launch_bounds__(256) void merge_kernel(const float* __restrict__ pred,
                                                    const float* __restrict__ targ,
                                                    const float* __restrict__ feat,
                                                    const float* __restrict__ pts,
                                                    const float4* __restrict__ cand,
                                                    float4* __restrict__ part,
                                                    unsigned* __restrict__ done,
                                                    float* __restrict__ out) {
  __shared__ float4 sh[256];
  __shared__ float ws4[4][4];
  __shared__ int is_last;
  constexpr int CPT = CHUNKS / 4;
  int tid  = threadIdx.x;
  int lane = tid & 63;
  int sub  = tid >> 6;
  int i = blockIdx.x * 64 + lane;

  const float4* f4 = (const float4*)feat;
  float s_sp = 0.f;
#pragma unroll
  for (int s = 0; s < 4; ++s) {
    float4 v = f4[(size_t)s * 65536 + blockIdx.x * 256 + tid];
    s_sp += fabsf(v.x) + fabsf(v.y) + fabsf(v.z) + fabsf(v.w);
  }

  float b0 = FLT_MAX, b1 = FLT_MAX, b2 = FLT_MAX, b3 = FLT_MAX;
#pragma unroll 4
  for (int cc = 0; cc < CPT; ++cc) {
    float4 v = cand[(size_t)(sub * CPT + cc) * N_ + i];
    ins4f(v.x, b0, b1, b2, b3);
    ins4f(v.y, b0, b1, b2, b3);
    ins4f(v.z, b0, b1, b2, b3);
    ins4f(v.w, b0, b1, b2, b3);
  }
  sh[tid] = make_float4(b0, b1, b2, b3);
  __syncthreads();

  float s_occ = 0.f, s_cons = 0.f, s_sm = 0.f;
  if (sub == 0) {
#pragma unroll
    for (int w = 1; w < 4; ++w) {
      float4 v = sh[w * 64 + lane];
      ins4f(v.x, b0, b1, b2, b3);
      ins4f(v.y, b0, b1, b2, b3);
      ins4f(v.z, b0, b1, b2, b3);
      ins4f(v.w, b0, b1, b2, b3);
    }
    unsigned qarr[4] = {__float_as_uint(b0) & 0xFFFu, __float_as_uint(b1) & 0xFFFu,
                        __float_as_uint(b2) & 0xFFFu, __float_as_uint(b3) & 0xFFFu};
    float xi = pts[3 * i], yi = pts[3 * i + 1], zi = pts[3 * i + 2];
    float c0 = FLT_MAX, c1 = FLT_MAX, c2 = FLT_MAX;
    float p0 = 0.f, p1 = 0.f, p2 = 0.f;
#pragma unroll
    for (int s = 0; s < 4; ++s) {
#pragma unroll
      for (int m = 0; m < 8; ++m) {
        int j = (int)(qarr[s] * 8 + m);
        float dx = xi - pts[3 * j], dy = yi - pts[3 * j + 1], dz = zi - pts[3 * j + 2];
        float d2 = fmaf(dx, dx, fmaf(dy, dy, dz * dz));
        float pj = pred[j];
        if (j != i && d2 < c2) {                   // exact top-3, self excluded by index
          bool cc0 = d2 < c0, cc1 = d2 < c1;
          float n2 = cc1 ? c1 : d2;               float m2 = cc1 ? p1 : pj;
          float n1 = cc0 ? c0 : (cc1 ? d2 : c1);  float m1 = cc0 ? p0 : (cc1 ? pj : p1);
          float n0 = cc0 ? d2 : c0;               float m0 = cc0 ? pj : p0;
          c0 = n0; c1 = n1; c2 = n2; p0 = m0; p1 = m1; p2 = m2;
        }
      }
    }
    float pi = pred[i], tg = targ[i];
    float p  = fminf(fmaxf(pi, EPS_), 1.0f - EPS_);
    s_occ  = -(tg * __logf(p) + (1.0f - tg) * __logf(1.0f - p));
    float dd = pi - tg;
    s_cons = dd * dd;
    s_sm   = fabsf(pi - p0) + fabsf(pi - p1) + fabsf(pi - p2);
  }

  for (int off = 32; off > 0; off >>= 1) {
    s_sp   += __shfl_down(s_sp, off);
    s_occ  += __shfl_down(s_occ, off);
    s_cons += __shfl_down(s_cons, off);
    s_sm   += __shfl_down(s_sm, off);
  }
  if ((tid & 63) == 0) {
    int w = tid >> 6;
    ws4[w][0] = s_occ; ws4[w][1] = s_cons; ws4[w][2] = s_sp; ws4[w][3] = s_sm;
  }
  __syncthreads();
  if (tid == 0) {
    part[blockIdx.x] = make_float4(ws4[0][0] + ws4[1][0] + ws4[2][0] + ws4[3][0],
                                   ws4[0][1] + ws4[1][1] + ws4[2][1] + ws4[3][1],
                                   ws4[0][2] + ws4[1][2] + ws4[2][2] + ws4[3][2],
                                   ws4[0][3] + ws4[1][3] + ws4[2][3] + ws4[3][3]);
    __threadfence();
    unsigned prev = atomicAdd(done, 1u);
    is_last = (prev == (unsigned)(gridDim.x - 1));
  }
  __syncthreads();

  if (is_last) {
    __threadfence();
    float4 a = part[tid];
    float o = a.x, cn = a.y, sp = a.z, sm = a.w;
    for (int off = 32; off > 0; off >>= 1) {
      o  += __shfl_down(o, off);
      cn += __shfl_down(cn, off);
      sp += __shfl_down(sp, off);
      sm += __shfl_down(sm, off);
    }
    if ((tid & 63) == 0) {
      int w = tid >> 6;
      ws4[w][0] = o; ws4[w][1] = cn; ws4[w][2] = sp; ws4[w][3] = sm;
    }
    __syncthreads();
    if (tid == 0) {
      float occ  = ws4[0][0] + ws4[1][0] + ws4[2][0] + ws4[3][0];
      float cons = ws4[0][1] + ws4[1][1] + ws4[2][1] + ws4[3][1];
      float spar = ws4[0][2] + ws4[1][2] + ws4[2][2] + ws4[3][2];
      float smoo = ws4[0][3] + ws4[1][3] + ws4[2][3] + ws4[3][3];
      out[0] = OCC_W * (occ / (float)N_)
             + CONS_W * (cons / (float)N_)
             + SPARSE_W * (spar / (float)(N_ * F_))
             + SMOOTH_W * (smoo / (float)(N_ * 3));
    }
  }
}

extern "C" void kernel_launch(void* const* d_in, const int* in_sizes, int n_in,
                              void* d_out, int out_size, void* d_ws, size_t ws_size,
                              hipStream_t stream) {
  const float* pred = (const float*)d_in[0];
  const float* targ = (const float*)d_in[1];
  const float* feat = (const float*)d_in[2];
  const float* pts  = (const float*)d_in[3];
  float* out = (float*)d_out;

  char*     ws   = (char*)d_ws;
  float4*   part = (float4*)ws;
  unsigned* done = (unsigned*)(ws + 4096);
  float4*   cand = (float4*)(ws + 8192);

  size_t base = 8192;
  auto need = [&](int c) { return base + (size_t)c * N_ * 16; };
  if (ws_size >= need(64)) {
    knn_kernel<64><<<8 * 64, 256, 0, stream>>>(pts, cand, done);
    merge_kernel<64><<<256, 256, 0, stream>>>(pred, targ, feat, pts, cand, part, done, out);
  } else if (ws_size >= need(32)) {
    knn_kernel<32><<<8 * 32, 256, 0, stream>>>(pts, cand, done);
    merge_kernel<32><<<256, 256, 0, stream>>>(pred, targ, feat, pts, cand, part, done, out);
  } else {
    knn_kernel<16><<<8 * 16, 256, 0, stream>>>(pts, cand, done);
    merge_kernel<16><<<256, 256, 0, stream>>>(pred, targ, feat, pts, cand, part, done, out);
  }
}

// Round 14
// 110.419 us; speedup vs baseline: 1.0980x; 1.0980x over previous
//
#include <hip/hip_runtime.h>
#include <float.h>
#include <math.h>

// AdvancedLossFunction: total = 1.0*occ + 0.1*smooth + 0.01*sparse + 0.1*cons
// 2 dispatches. 3-NN via OCTET-min packed-key brute force:
//   t(i,j) = -2 p_i.q_j + |q_j|^2  (monotone in d2 per i)
//   knn keeps top-4 of per-octet (8 j's) minima:
//     key = bits(min t of octet) & 0xFFFFF000 | octet_id (11 bits).
//   Coverage: points with t <= t(NN3) are {self,NN1..NN3} -> occupy <= 4 octets ->
//   top-4 octet keys always cover them. Merge decodes 4 octets -> 32 candidates,
//   re-evaluates EXACT d2 with index self-exclusion -> absmax ~ 0.
// R13 lesson: v_pk_fma inline asm costs hidden v_movs (VALU time 2.3x ideal) ->
//   scalar fmaf, 4.6 flat ops/pair. Stall factor attacked with explicit register
//   double-buffering of the octet's 8 float4s (lgkmcnt overlaps 148-inst compute).
// R9/R10: occupancy irrelevant. R7: flat > branchy. R6/R10: no bulk fences.

constexpr int   N_ = 16384;
constexpr int   F_ = 64;
constexpr float OCC_W = 1.0f, SMOOTH_W = 0.1f, SPARSE_W = 0.01f, CONS_W = 0.1f;
constexpr float EPS_ = 1e-7f;

__device__ __forceinline__ void ins4f(float t, float& b0, float& b1, float& b2, float& b3) {
  // maintains b0<=b1<=b2<=b3; med3(a,b,t) with a<=b == sorted-insert clamp
  float n0 = fminf(b0, t);
  float n1 = __builtin_amdgcn_fmed3f(b0, b1, t);
  float n2 = __builtin_amdgcn_fmed3f(b1, b2, t);
  float n3 = __builtin_amdgcn_fmed3f(b2, b3, t);
  b0 = n0; b1 = n1; b2 = n2; b3 = n3;
}

// ws layout:
//   0    : float4 part[256]
//   4096 : unsigned done          (zeroed by knn block 0)
//   8192 : float4 cand[CHUNKS][N] (top-4 packed octet keys per (chunk, i))

template <int CHUNKS>
__global__ __launch_bounds__(256) void knn_kernel(const float* __restrict__ pts,
                                                  float4* __restrict__ cand,
                                                  unsigned* __restrict__ done) {
  constexpr int CHUNK   = N_ / CHUNKS;             // 256 at CHUNKS=64
  constexpr int TILE    = CHUNK;
  constexpr int NOCT    = TILE / 8;                // 32
  constexpr int ITEMS   = 4;
  constexpr int IPG     = 1024;
  constexpr int IGROUPS = N_ / IPG;                // 16
  if (blockIdx.x == 0 && threadIdx.x == 0) *done = 0u;

  int igrp  = blockIdx.x % IGROUPS;
  int chunk = blockIdx.x / IGROUPS;
  int j0    = chunk * CHUNK;

  // SoA per j: Q[j] = (-2x, -2y, -2z, |q|^2)
  __shared__ float4 Q[TILE];
  for (int t = threadIdx.x; t < TILE; t += 256) {
    int j = j0 + t;
    float x = pts[3 * j], y = pts[3 * j + 1], z = pts[3 * j + 2];
    Q[t] = make_float4(-2.f * x, -2.f * y, -2.f * z, fmaf(x, x, fmaf(y, y, z * z)));
  }

  float xi[ITEMS], yi[ITEMS], zi[ITEMS];
  float b0[ITEMS], b1[ITEMS], b2[ITEMS], b3[ITEMS];
#pragma unroll
  for (int k = 0; k < ITEMS; ++k) {
    int i = igrp * IPG + threadIdx.x + k * 256;
    xi[k] = pts[3 * i]; yi[k] = pts[3 * i + 1]; zi[k] = pts[3 * i + 2];
    b0[k] = b1[k] = b2[k] = b3[k] = FLT_MAX;
  }
  __syncthreads();

  unsigned obase = (unsigned)(j0 >> 3);            // global octet id base (2048 octets)

  // register double-buffer: load octet o+1 while computing octet o
  float4 c0 = Q[0], c1 = Q[1], c2 = Q[2], c3 = Q[3],
         c4 = Q[4], c5 = Q[5], c6 = Q[6], c7 = Q[7];
  for (int oct = 0; oct < NOCT; ++oct) {
    int nb = ((oct + 1) & (NOCT - 1)) * 8;         // wraps on last iter (harmless)
    float4 n0 = Q[nb + 0], n1 = Q[nb + 1], n2 = Q[nb + 2], n3 = Q[nb + 3],
           n4 = Q[nb + 4], n5 = Q[nb + 5], n6 = Q[nb + 6], n7 = Q[nb + 7];
    unsigned ok = obase + (unsigned)oct;
#pragma unroll
    for (int k = 0; k < ITEMS; ++k) {
      float x = xi[k], y = yi[k], z = zi[k];
      float t0 = fmaf(x, c0.x, fmaf(y, c0.y, fmaf(z, c0.z, c0.w)));
      float t1 = fmaf(x, c1.x, fmaf(y, c1.y, fmaf(z, c1.z, c1.w)));
      float t2 = fmaf(x, c2.x, fmaf(y, c2.y, fmaf(z, c2.z, c2.w)));
      float t3 = fmaf(x, c3.x, fmaf(y, c3.y, fmaf(z, c3.z, c3.w)));
      float t4 = fmaf(x, c4.x, fmaf(y, c4.y, fmaf(z, c4.z, c4.w)));
      float t5 = fmaf(x, c5.x, fmaf(y, c5.y, fmaf(z, c5.z, c5.w)));
      float t6 = fmaf(x, c6.x, fmaf(y, c6.y, fmaf(z, c6.z, c6.w)));
      float t7 = fmaf(x, c7.x, fmaf(y, c7.y, fmaf(z, c7.z, c7.w)));
      float m = fminf(fminf(fminf(t0, t1), fminf(t2, t3)),
                      fminf(fminf(t4, t5), fminf(t6, t7)));
      float kf = __uint_as_float((__float_as_uint(m) & 0xFFFFF000u) | ok);
      ins4f(kf, b0[k], b1[k], b2[k], b3[k]);       // 37 flat insts / 8 pairs / item
    }
    c0 = n0; c1 = n1; c2 = n2; c3 = n3; c4 = n4; c5 = n5; c6 = n6; c7 = n7;
  }

#pragma unroll
  for (int k = 0; k < ITEMS; ++k) {
    int i = igrp * IPG + threadIdx.x + k * 256;
    cand[(size_t)chunk * N_ + i] = make_float4(b0[k], b1[k], b2[k], b3[k]);
  }
}

// grid 256: 64 i's per block, 4 waves scan CHUNKS/4 chunks each; wave 0 merges,
// decodes 4 octets -> 32 candidates, exact d2 + index self-exclusion -> smoothness.
// Plus all scalar reductions. 256-block staggered ticket; last block finalizes.
template <int CHUNKS>
__global__ __launch_bounds__(256) void merge_kernel(const float* __restrict__ pred,
                                                    const float* __restrict__ targ,
                                                    const float* __restrict__ feat,
                                                    const float* __restrict__ pts,
                                                    const float4* __restrict__ cand,
                                                    float4* __restrict__ part,
                                                    unsigned* __restrict__ done,
                                                    float* __restrict__ out) {
  __shared__ float4 sh[256];
  __shared__ float ws4[4][4];
  __shared__ int is_last;
  constexpr int CPT = CHUNKS / 4;
  int tid  = threadIdx.x;
  int lane = tid & 63;
  int sub  = tid >> 6;
  int i = blockIdx.x * 64 + lane;

  const float4* f4 = (const float4*)feat;
  float s_sp = 0.f;
#pragma unroll
  for (int s = 0; s < 4; ++s) {
    float4 v = f4[(size_t)s * 65536 + blockIdx.x * 256 + tid];
    s_sp += fabsf(v.x) + fabsf(v.y) + fabsf(v.z) + fabsf(v.w);
  }

  float b0 = FLT_MAX, b1 = FLT_MAX, b2 = FLT_MAX, b3 = FLT_MAX;
#pragma unroll 4
  for (int cc = 0; cc < CPT; ++cc) {
    float4 v = cand[(size_t)(sub * CPT + cc) * N_ + i];
    ins4f(v.x, b0, b1, b2, b3);
    ins4f(v.y, b0, b1, b2, b3);
    ins4f(v.z, b0, b1, b2, b3);
    ins4f(v.w, b0, b1, b2, b3);
  }
  sh[tid] = make_float4(b0, b1, b2, b3);
  __syncthreads();

  float s_occ = 0.f, s_cons = 0.f, s_sm = 0.f;
  if (sub == 0) {
#pragma unroll
    for (int w = 1; w < 4; ++w) {
      float4 v = sh[w * 64 + lane];
      ins4f(v.x, b0, b1, b2, b3);
      ins4f(v.y, b0, b1, b2, b3);
      ins4f(v.z, b0, b1, b2, b3);
      ins4f(v.w, b0, b1, b2, b3);
    }
    unsigned qarr[4] = {__float_as_uint(b0) & 0xFFFu, __float_as_uint(b1) & 0xFFFu,
                        __float_as_uint(b2) & 0xFFFu, __float_as_uint(b3) & 0xFFFu};
    float xi = pts[3 * i], yi = pts[3 * i + 1], zi = pts[3 * i + 2];
    float c0 = FLT_MAX, c1 = FLT_MAX, c2 = FLT_MAX;
    float p0 = 0.f, p1 = 0.f, p2 = 0.f;
#pragma unroll
    for (int s = 0; s < 4; ++s) {
#pragma unroll
      for (int m = 0; m < 8; ++m) {
        int j = (int)(qarr[s] * 8 + m);
        float dx = xi - pts[3 * j], dy = yi - pts[3 * j + 1], dz = zi - pts[3 * j + 2];
        float d2 = fmaf(dx, dx, fmaf(dy, dy, dz * dz));
        float pj = pred[j];
        if (j != i && d2 < c2) {                   // exact top-3, self excluded by index
          bool cc0 = d2 < c0, cc1 = d2 < c1;
          float n2 = cc1 ? c1 : d2;               float m2 = cc1 ? p1 : pj;
          float n1 = cc0 ? c0 : (cc1 ? d2 : c1);  float m1 = cc0 ? p0 : (cc1 ? pj : p1);
          float n0 = cc0 ? d2 : c0;               float m0 = cc0 ? pj : p0;
          c0 = n0; c1 = n1; c2 = n2; p0 = m0; p1 = m1; p2 = m2;
        }
      }
    }
    float pi = pred[i], tg = targ[i];
    float p  = fminf(fmaxf(pi, EPS_), 1.0f - EPS_);
    s_occ  = -(tg * __logf(p) + (1.0f - tg) * __logf(1.0f - p));
    float dd = pi - tg;
    s_cons = dd * dd;
    s_sm   = fabsf(pi - p0) + fabsf(pi - p1) + fabsf(pi - p2);
  }

  for (int off = 32; off > 0; off >>= 1) {
    s_sp   += __shfl_down(s_sp, off);
    s_occ  += __shfl_down(s_occ, off);
    s_cons += __shfl_down(s_cons, off);
    s_sm   += __shfl_down(s_sm, off);
  }
  if ((tid & 63) == 0) {
    int w = tid >> 6;
    ws4[w][0] = s_occ; ws4[w][1] = s_cons; ws4[w][2] = s_sp; ws4[w][3] = s_sm;
  }
  __syncthreads();
  if (tid == 0) {
    part[blockIdx.x] = make_float4(ws4[0][0] + ws4[1][0] + ws4[2][0] + ws4[3][0],
                                   ws4[0][1] + ws4[1][1] + ws4[2][1] + ws4[3][1],
                                   ws4[0][2] + ws4[1][2] + ws4[2][2] + ws4[3][2],
                                   ws4[0][3] + ws4[1][3] + ws4[2][3] + ws4[3][3]);
    __threadfence();
    unsigned prev = atomicAdd(done, 1u);
    is_last = (prev == (unsigned)(gridDim.x - 1));
  }
  __syncthreads();

  if (is_last) {
    __threadfence();
    float4 a = part[tid];
    float o = a.x, cn = a.y, sp = a.z, sm = a.w;
    for (int off = 32; off > 0; off >>= 1) {
      o  += __shfl_down(o, off);
      cn += __shfl_down(cn, off);
      sp += __shfl_down(sp, off);
      sm += __shfl_down(sm, off);
    }
    if ((tid & 63) == 0) {
      int w = tid >> 6;
      ws4[w][0] = o; ws4[w][1] = cn; ws4[w][2] = sp; ws4[w][3] = sm;
    }
    __syncthreads();
    if (tid == 0) {
      float occ  = ws4[0][0] + ws4[1][0] + ws4[2][0] + ws4[3][0];
      float cons = ws4[0][1] + ws4[1][1] + ws4[2][1] + ws4[3][1];
      float spar = ws4[0][2] + ws4[1][2] + ws4[2][2] + ws4[3][2];
      float smoo = ws4[0][3] + ws4[1][3] + ws4[2][3] + ws4[3][3];
      out[0] = OCC_W * (occ / (float)N_)
             + CONS_W * (cons / (float)N_)
             + SPARSE_W * (spar / (float)(N_ * F_))
             + SMOOTH_W * (smoo / (float)(N_ * 3));
    }
  }
}

extern "C" void kernel_launch(void* const* d_in, const int* in_sizes, int n_in,
                              void* d_out, int out_size, void* d_ws, size_t ws_size,
                              hipStream_t stream) {
  const float* pred = (const float*)d_in[0];
  const float* targ = (const float*)d_in[1];
  const float* feat = (const float*)d_in[2];
  const float* pts  = (const float*)d_in[3];
  float* out = (float*)d_out;

  char*     ws   = (char*)d_ws;
  float4*   part = (float4*)ws;
  unsigned* done = (unsigned*)(ws + 4096);
  float4*   cand = (float4*)(ws + 8192);

  size_t base = 8192;
  auto need = [&](int c) { return base + (size_t)c * N_ * 16; };
  if (ws_size >= need(64)) {
    knn_kernel<64><<<16 * 64, 256, 0, stream>>>(pts, cand, done);
    merge_kernel<64><<<256, 256, 0, stream>>>(pred, targ, feat, pts, cand, part, done, out);
  } else if (ws_size >= need(32)) {
    knn_kernel<32><<<16 * 32, 256, 0, stream>>>(pts, cand, done);
    merge_kernel<32><<<256, 256, 0, stream>>>(pred, targ, feat, pts, cand, part, done, out);
  } else {
    knn_kernel<16><<<16 * 16, 256, 0, stream>>>(pts, cand, done);
    merge_kernel<16><<<256, 256, 0, stream>>>(pred, targ, feat, pts, cand, part, done, out);
  }
}